// Round 10
// baseline (396.495 us; speedup 1.0000x reference)
//
#include <hip/hip_runtime.h>
#include <hip/hip_bf16.h>

#define T_ 256
#define B_ 16
#define S_ 64
#define D_ 256

typedef __attribute__((ext_vector_type(4))) int int4v;

__device__ __forceinline__ float tanh_fast(float x) {
    // tanh(x) = 1 - 2/(1+exp(2x)); saturates correctly at +-inf
    float e = __expf(2.0f * x);
    float r = __builtin_amdgcn_rcpf(e + 1.0f);
    return __builtin_fmaf(-2.0f, r, 1.0f);
}

// LDS-visibility-only barrier: waits DS ops, leaves global loads/stores/atomics
// in flight across the barrier (avoids the __syncthreads vmcnt(0) drain).
#define LDS_BARRIER() asm volatile("s_waitcnt lgkmcnt(0)\n\ts_barrier" ::: "memory")

// ---------------- W_x transpose: WxT[k][d] = W_x[d][k] ----------------
__global__ void k_transpose(const float* __restrict__ in, float* __restrict__ out) {
    __shared__ float tile[32][33];
    int tx = threadIdx.x & 31, ty = threadIdx.x >> 5;
    int bx = blockIdx.x & 7, by = blockIdx.x >> 3;
    tile[ty][tx] = in[(by * 32 + ty) * D_ + bx * 32 + tx];
    __syncthreads();
    out[(bx * 32 + ty) * D_ + by * 32 + tx] = tile[tx][ty];
}

// ---- wz[t*B+b][d] = { bias[d] + sum_k x[t,b,k]*WxT[k][d],  silu(z[t,b,d]) } ----
__global__ __launch_bounds__(256) void k_wxall(const float* __restrict__ x,
                                               const float* __restrict__ z,
                                               const float* __restrict__ WxT,
                                               const float* __restrict__ bias,
                                               float2* __restrict__ wz) {
    __shared__ float xs[16][D_];
    const int tid = threadIdx.x;
    const int row0 = blockIdx.x * 16;
    for (int r = 0; r < 16; ++r)
        xs[r][tid] = x[(size_t)(row0 + r) * D_ + tid];
    __syncthreads();
    float acc[16];
    float bv = bias[tid];
#pragma unroll
    for (int r = 0; r < 16; ++r) acc[r] = bv;
    for (int k = 0; k < D_; ++k) {
        float wv = WxT[k * D_ + tid];
#pragma unroll
        for (int r = 0; r < 16; ++r) acc[r] = __builtin_fmaf(wv, xs[r][k], acc[r]);
    }
    for (int r = 0; r < 16; ++r) {
        float zv = z[(size_t)(row0 + r) * D_ + tid];
        float sil = zv * __builtin_amdgcn_rcpf(1.0f + __expf(-zv));
        wz[(size_t)(row0 + r) * D_ + tid] = make_float2(acc[r], sil);
    }
}

// ---------------- main recurrence (i8 MFMA K=64, 4 slots, 4 waves) ----------------
// grid = 256 blocks: block -> (b = blk>>4, slots s0..s0+3, s0 = (blk&15)*4)
// block = 256 threads = 4 waves (1/SIMD); wave w owns n-slice [64w, 64w+64).
// Why 4 waves (not 8): the A-fragment LDS reads are identical across waves, so
// the per-CU post-barrier LDS burst scales with wave count (8 waves = 32 b128
// = ~380 cyc of the shared LDS pipe; 4 waves = ~190). MFMA issue/SIMD is
// unchanged (16 MFMA x ~20 cyc, 1 wave/SIMD).
// Epilogue: thread col d = 64w + lane -> nt = quad, and slot = C reg index, so
// each thread holds ALL 4 slots of its column: no shfl, 1 atomic/lane.
__global__ __launch_bounds__(256, 1) void k_rec(
    const float* __restrict__ Wh,      // [D][D] (n-major: Wh[n][k])
    const float2* __restrict__ wz,     // [T*B][D] {wx+bias, silu(z)}
    const float* __restrict__ h0,      // [B][S][D]
    const float* __restrict__ Cvec,    // [S]
    float* __restrict__ outputs,       // [T*B][D], pre-zeroed (atomic accum)
    float* __restrict__ h_out)         // [(T+1)*B][S][D]
{
    const int tid  = threadIdx.x;
    const int w    = tid >> 6;
    const int lane = tid & 63;
    const int l16  = lane & 15;
    const int quad = lane >> 4;
    const int b    = blockIdx.x >> 4;
    const int s0   = (blockIdx.x & 15) * 4;
    const int d    = (w << 6) | lane;          // this thread's output column

    // ping-pong h buffer, i8. Row stride 288 B: the 16 distinct b128 A-chunks
    // land 2-way per bank (free, m136); b8 writes showed 0 conflicts R3-R9.
    __shared__ __align__(16) signed char hA8[2][4][288];

    // init hA8[0] from h0 and write h[0] = h0  (256 threads, 4 iters)
    for (int i = tid; i < 4 * D_; i += 256) {
        int r = i >> 8, dd = i & 255;
        float v = h0[(size_t)(b * S_ + s0 + r) * D_ + dd];
        float vc = fminf(fmaxf(v, -1.0f), 1.0f);
        hA8[0][r][dd] = (signed char)__float2int_rn(vc * 127.0f);
        h_out[(size_t)(b * S_ + s0 + r) * D_ + dd] = v;
    }

    // ---- pass 1: per-column absmax of Wh for cols n = 64w + nt*16 + l16 ----
    float cmax[4];
#pragma unroll
    for (int nt = 0; nt < 4; ++nt) {
        const float* wr = Wh + (size_t)(w * 64 + nt * 16 + l16) * D_ + quad * 16;
        float cm = 1e-20f;
#pragma unroll
        for (int kt = 0; kt < 4; ++kt) {
            const float* p = wr + kt * 64;
#pragma unroll
            for (int j = 0; j < 16; j += 4) {
                float4 v = *(const float4*)(p + j);
                cm = fmaxf(cm, fmaxf(fmaxf(fabsf(v.x), fabsf(v.y)),
                                     fmaxf(fabsf(v.z), fabsf(v.w))));
            }
        }
        cm = fmaxf(cm, __shfl_xor(cm, 16, 64));
        cm = fmaxf(cm, __shfl_xor(cm, 32, 64));
        cmax[nt] = cm;
    }

    // ---- pass 2: quantize Wh -> i8 B-fragments (64 VGPRs) ----
    // lane holds B[k = kt*64 + quad*16 + j][n = 64w + nt*16 + l16]
    int4v Bf[4][4];
#pragma unroll
    for (int nt = 0; nt < 4; ++nt) {
        const float rs = 127.0f / cmax[nt];
        const float* wr = Wh + (size_t)(w * 64 + nt * 16 + l16) * D_ + quad * 16;
#pragma unroll
        for (int kt = 0; kt < 4; ++kt) {
            const float* p = wr + kt * 64;
            int4v frag;
#pragma unroll
            for (int r = 0; r < 4; ++r) {
                float4 v = *(const float4*)(p + r * 4);
                int q0 = __float2int_rn(v.x * rs) & 255;
                int q1 = __float2int_rn(v.y * rs) & 255;
                int q2 = __float2int_rn(v.z * rs) & 255;
                int q3 = __float2int_rn(v.w * rs) & 255;
                frag[r] = q0 | (q1 << 8) | (q2 << 16) | (q3 << 24);
            }
            Bf[kt][nt] = frag;
        }
    }
    // this thread's column scale: col d -> nt = quad  (runtime select x3)
    float ds01 = (quad & 1) ? cmax[1] : cmax[0];
    float ds23 = (quad & 1) ? cmax[3] : cmax[2];
    const float dscale = ((quad & 2) ? ds23 : ds01) * (1.0f / 16129.0f);
    const float c0 = Cvec[s0], c1 = Cvec[s0 + 1], c2 = Cvec[s0 + 2], c3 = Cvec[s0 + 3];

    // prologue: wz for t=0 and t=1; running pointers
    const float2* wzp = wz + (size_t)b * D_ + d;
    float2 wzr[2];
    wzr[0] = wzp[0];
    wzr[1] = wzp[(size_t)B_ * D_];
    wzp += (size_t)2 * B_ * D_;                 // points at t=2's row

    // deferred output state of step t-1 (flushed in step t's ds_read shadow)
    float fh0 = 0.f, fh1 = 0.f, fh2 = 0.f, fh3 = 0.f, fos = 0.f;
    float* hp = h_out + (size_t)(1 * B_ + b) * (S_ * D_) + (size_t)s0 * D_ + d;
    float* op = outputs + (size_t)b * D_ + d;

    const int4v Zc = {0, 0, 0, 0};   // persistent zero C operand (hoisted)

    __syncthreads();   // full barrier once (init visibility incl. global)

#define STEP(t, CUR, NXT)                                                      \
    {                                                                          \
        const signed char* ap = &hA8[CUR][l16 & 3][quad * 16];                 \
        int4v Af0 = *(const int4v*)(ap);                                       \
        int4v Af1 = *(const int4v*)(ap + 64);                                  \
        int4v Af2 = *(const int4v*)(ap + 128);                                 \
        int4v Af3 = *(const int4v*)(ap + 192);                                 \
        if ((t) >= 1) { /* step t-1's output path, in the ds_read shadow */    \
            __builtin_nontemporal_store(fh0, hp);                              \
            __builtin_nontemporal_store(fh1, hp + D_);                         \
            __builtin_nontemporal_store(fh2, hp + 2 * D_);                     \
            __builtin_nontemporal_store(fh3, hp + 3 * D_);                     \
            hp += B_ * S_ * D_;                                                \
            atomicAdd(op, fos);                                                \
            op += B_ * D_;                                                     \
        }                                                                      \
        float wx  = wzr[CUR].x;                                                \
        float sil = wzr[CUR].y;                                                \
        wzr[CUR] = *wzp;                      /* load for t+2, 2-step cover */ \
        wzp += ((t) < T_ - 2) ? (size_t)B_ * D_ : 0;                           \
        /* 4 independent 4-deep MFMA chains; dep pairs 4 instrs apart */       \
        int4v a0, a1, a2, a3;                                                  \
        a0 = __builtin_amdgcn_mfma_i32_16x16x64_i8(Af0, Bf[0][0], Zc, 0, 0, 0); \
        a1 = __builtin_amdgcn_mfma_i32_16x16x64_i8(Af0, Bf[0][1], Zc, 0, 0, 0); \
        a2 = __builtin_amdgcn_mfma_i32_16x16x64_i8(Af0, Bf[0][2], Zc, 0, 0, 0); \
        a3 = __builtin_amdgcn_mfma_i32_16x16x64_i8(Af0, Bf[0][3], Zc, 0, 0, 0); \
        a0 = __builtin_amdgcn_mfma_i32_16x16x64_i8(Af1, Bf[1][0], a0, 0, 0, 0); \
        a1 = __builtin_amdgcn_mfma_i32_16x16x64_i8(Af1, Bf[1][1], a1, 0, 0, 0); \
        a2 = __builtin_amdgcn_mfma_i32_16x16x64_i8(Af1, Bf[1][2], a2, 0, 0, 0); \
        a3 = __builtin_amdgcn_mfma_i32_16x16x64_i8(Af1, Bf[1][3], a3, 0, 0, 0); \
        a0 = __builtin_amdgcn_mfma_i32_16x16x64_i8(Af2, Bf[2][0], a0, 0, 0, 0); \
        a1 = __builtin_amdgcn_mfma_i32_16x16x64_i8(Af2, Bf[2][1], a1, 0, 0, 0); \
        a2 = __builtin_amdgcn_mfma_i32_16x16x64_i8(Af2, Bf[2][2], a2, 0, 0, 0); \
        a3 = __builtin_amdgcn_mfma_i32_16x16x64_i8(Af2, Bf[2][3], a3, 0, 0, 0); \
        a0 = __builtin_amdgcn_mfma_i32_16x16x64_i8(Af3, Bf[3][0], a0, 0, 0, 0); \
        a1 = __builtin_amdgcn_mfma_i32_16x16x64_i8(Af3, Bf[3][1], a1, 0, 0, 0); \
        a2 = __builtin_amdgcn_mfma_i32_16x16x64_i8(Af3, Bf[3][2], a2, 0, 0, 0); \
        a3 = __builtin_amdgcn_mfma_i32_16x16x64_i8(Af3, Bf[3][3], a3, 0, 0, 0); \
        /* col d -> nt = quad; slot r = C reg index. Select acc[quad][r]. */   \
        int s0v = (quad & 2) ? ((quad & 1) ? a3[0] : a2[0])                    \
                             : ((quad & 1) ? a1[0] : a0[0]);                   \
        int s1v = (quad & 2) ? ((quad & 1) ? a3[1] : a2[1])                    \
                             : ((quad & 1) ? a1[1] : a0[1]);                   \
        int s2v = (quad & 2) ? ((quad & 1) ? a3[2] : a2[2])                    \
                             : ((quad & 1) ? a1[2] : a0[2]);                   \
        int s3v = (quad & 2) ? ((quad & 1) ? a3[3] : a2[3])                    \
                             : ((quad & 1) ? a1[3] : a0[3]);                   \
        float hv0 = tanh_fast(__builtin_fmaf((float)s0v, dscale, wx));         \
        float hv1 = tanh_fast(__builtin_fmaf((float)s1v, dscale, wx));         \
        float hv2 = tanh_fast(__builtin_fmaf((float)s2v, dscale, wx));         \
        float hv3 = tanh_fast(__builtin_fmaf((float)s3v, dscale, wx));         \
        hA8[NXT][0][d] = (signed char)__float2int_rn(hv0 * 127.0f);            \
        hA8[NXT][1][d] = (signed char)__float2int_rn(hv1 * 127.0f);            \
        hA8[NXT][2][d] = (signed char)__float2int_rn(hv2 * 127.0f);            \
        hA8[NXT][3][d] = (signed char)__float2int_rn(hv3 * 127.0f);            \
        fh0 = hv0; fh1 = hv1; fh2 = hv2; fh3 = hv3;                            \
        float pa = __builtin_fmaf(c0, hv0, c1 * hv1);                          \
        float pb = __builtin_fmaf(c2, hv2, c3 * hv3);                          \
        fos = (pa + pb) * sil;                                                 \
        LDS_BARRIER();                                                         \
    }

    for (int t2 = 0; t2 < T_; t2 += 2) {
        STEP(t2, 0, 1)
        STEP(t2 + 1, 1, 0)
    }
#undef STEP

    // tail: flush step T-1's output path
    __builtin_nontemporal_store(fh0, hp);
    __builtin_nontemporal_store(fh1, hp + D_);
    __builtin_nontemporal_store(fh2, hp + 2 * D_);
    __builtin_nontemporal_store(fh3, hp + 3 * D_);
    atomicAdd(op, fos);
}

extern "C" void kernel_launch(void* const* d_in, const int* in_sizes, int n_in,
                              void* d_out, int out_size, void* d_ws, size_t ws_size,
                              hipStream_t stream) {
    const float* x    = (const float*)d_in[0];
    const float* z    = (const float*)d_in[1];
    const float* h0   = (const float*)d_in[2];
    const float* W_x  = (const float*)d_in[3];
    const float* W_h  = (const float*)d_in[4];
    const float* bias = (const float*)d_in[5];
    const float* C    = (const float*)d_in[6];

    float* outputs = (float*)d_out;                     // [T*B*D]
    float* h_out   = outputs + (size_t)T_ * B_ * D_;    // [(T+1)*B*S*D]

    float*  WxT = (float*)d_ws;                         // D*D floats
    float2* wz  = (float2*)(WxT + D_ * D_);             // T*B*D float2

    hipMemsetAsync(outputs, 0, (size_t)T_ * B_ * D_ * sizeof(float), stream);
    k_transpose<<<64, 1024, 0, stream>>>(W_x, WxT);
    k_wxall<<<T_ * B_ / 16, 256, 0, stream>>>(x, z, WxT, bias, wz);
    k_rec<<<B_ * S_ / 4, 256, 0, stream>>>(W_h, wz, h0, C, outputs, h_out);
}

// Round 11
// 378.631 us; speedup vs baseline: 1.0472x; 1.0472x over previous
//
#include <hip/hip_runtime.h>
#include <hip/hip_bf16.h>

#define T_ 256
#define B_ 16
#define S_ 64
#define D_ 256

typedef __attribute__((ext_vector_type(4))) int int4v;

// LDS-visibility-only barrier: waits DS ops, leaves global loads/stores/atomics
// in flight across the barrier (avoids the __syncthreads vmcnt(0) drain).
#define LDS_BARRIER() asm volatile("s_waitcnt lgkmcnt(0)\n\ts_barrier" ::: "memory")

// ---------------- W_x transpose: WxT[k][d] = W_x[d][k] ----------------
__global__ void k_transpose(const float* __restrict__ in, float* __restrict__ out) {
    __shared__ float tile[32][33];
    int tx = threadIdx.x & 31, ty = threadIdx.x >> 5;
    int bx = blockIdx.x & 7, by = blockIdx.x >> 3;
    tile[ty][tx] = in[(by * 32 + ty) * D_ + bx * 32 + tx];
    __syncthreads();
    out[(bx * 32 + ty) * D_ + by * 32 + tx] = tile[tx][ty];
}

// ---- wz[t*B+b][d] = { bias[d] + sum_k x[t,b,k]*WxT[k][d],  silu(z[t,b,d]) } ----
__global__ __launch_bounds__(256) void k_wxall(const float* __restrict__ x,
                                               const float* __restrict__ z,
                                               const float* __restrict__ WxT,
                                               const float* __restrict__ bias,
                                               float2* __restrict__ wz) {
    __shared__ float xs[16][D_];
    const int tid = threadIdx.x;
    const int row0 = blockIdx.x * 16;
    for (int r = 0; r < 16; ++r)
        xs[r][tid] = x[(size_t)(row0 + r) * D_ + tid];
    __syncthreads();
    float acc[16];
    float bv = bias[tid];
#pragma unroll
    for (int r = 0; r < 16; ++r) acc[r] = bv;
    for (int k = 0; k < D_; ++k) {
        float wv = WxT[k * D_ + tid];
#pragma unroll
        for (int r = 0; r < 16; ++r) acc[r] = __builtin_fmaf(wv, xs[r][k], acc[r]);
    }
    for (int r = 0; r < 16; ++r) {
        float zv = z[(size_t)(row0 + r) * D_ + tid];
        float sil = zv * __builtin_amdgcn_rcpf(1.0f + __expf(-zv));
        wz[(size_t)(row0 + r) * D_ + tid] = make_float2(acc[r], sil);
    }
}

// ---------------- main recurrence (i8 MFMA K=64, 4 slots, 8 waves) ----------------
// grid = 256 blocks: block -> (b = blk>>4, slots s0..s0+3, s0 = (blk&15)*4)
// block = 512 threads = 8 waves (2/SIMD — best measured: waves pairwise hide
// latency; 4 waves (R10) and 16 waves (R5) both regressed).
// Pre-barrier tail minimized: LDS byte = 127*tanh(pre) computed as
// 127 - 254/(exp(2*pre)+1) (x2 folded into dscale2/wx2, x127 into one fma);
// ALL float post-processing (h/127, C-partial, silu) deferred to the next
// step's ds_read latency shadow.
__global__ __launch_bounds__(512, 1) void k_rec(
    const float* __restrict__ Wh,      // [D][D] (n-major: Wh[n][k])
    const float2* __restrict__ wz,     // [T*B][D] {wx+bias, silu(z)}
    const float* __restrict__ h0,      // [B][S][D]
    const float* __restrict__ Cvec,    // [S]
    float* __restrict__ outputs,       // [T*B][D], pre-zeroed (atomic accum)
    float* __restrict__ h_out)         // [(T+1)*B][S][D]
{
    const int tid  = threadIdx.x;
    const int w    = tid >> 6;
    const int lane = tid & 63;
    const int l16  = lane & 15;
    const int quad = lane >> 4;
    const int b    = blockIdx.x >> 4;
    const int s0   = (blockIdx.x & 15) * 4;
    const int r0   = quad & 2;                 // slot-pair this thread finalizes
    const int d    = (w << 5) | (lane & 31);   // this thread's output column

    // ping-pong h buffer, i8. Row stride 288 B: the 16 distinct b128 A-chunks
    // land 2-way per bank (free, m136); b8 writes showed 0 conflicts R3-R10.
    __shared__ __align__(16) signed char hA8[2][4][288];

    // init hA8[0] from h0 and write h[0] = h0  (512 threads, 2 iters)
    for (int i = tid; i < 4 * D_; i += 512) {
        int r = i >> 8, dd = i & 255;
        float v = h0[(size_t)(b * S_ + s0 + r) * D_ + dd];
        float vc = fminf(fmaxf(v, -1.0f), 1.0f);
        hA8[0][r][dd] = (signed char)__float2int_rn(vc * 127.0f);
        h_out[(size_t)(b * S_ + s0 + r) * D_ + dd] = v;
    }

    // ---- pass 1: per-column absmax of Wh for cols n = 32w + nt*16 + l16 ----
    float cmax[2];
#pragma unroll
    for (int nt = 0; nt < 2; ++nt) {
        const float* wr = Wh + (size_t)(w * 32 + nt * 16 + l16) * D_ + quad * 16;
        float cm = 1e-20f;
#pragma unroll
        for (int kt = 0; kt < 4; ++kt) {
            const float* p = wr + kt * 64;
#pragma unroll
            for (int j = 0; j < 16; j += 4) {
                float4 v = *(const float4*)(p + j);
                cm = fmaxf(cm, fmaxf(fmaxf(fabsf(v.x), fabsf(v.y)),
                                     fmaxf(fabsf(v.z), fabsf(v.w))));
            }
        }
        cm = fmaxf(cm, __shfl_xor(cm, 16, 64));
        cm = fmaxf(cm, __shfl_xor(cm, 32, 64));
        cmax[nt] = cm;
    }

    // ---- pass 2: quantize Wh -> i8 B-fragments (32 VGPRs) ----
    // lane holds B[k = kt*64 + quad*16 + j][n = 32w + nt*16 + l16]
    int4v Bf[4][2];
#pragma unroll
    for (int nt = 0; nt < 2; ++nt) {
        const float rs = 127.0f / cmax[nt];
        const float* wr = Wh + (size_t)(w * 32 + nt * 16 + l16) * D_ + quad * 16;
#pragma unroll
        for (int kt = 0; kt < 4; ++kt) {
            const float* p = wr + kt * 64;
            int4v frag;
#pragma unroll
            for (int r = 0; r < 4; ++r) {
                float4 v = *(const float4*)(p + r * 4);
                int q0 = __float2int_rn(v.x * rs) & 255;
                int q1 = __float2int_rn(v.y * rs) & 255;
                int q2 = __float2int_rn(v.z * rs) & 255;
                int q3 = __float2int_rn(v.w * rs) & 255;
                frag[r] = q0 | (q1 << 8) | (q2 << 16) | (q3 << 24);
            }
            Bf[kt][nt] = frag;
        }
    }
    // dequant scale folded with the tanh x2: pre2 = 2*(acc*dscale + wx)
    const float dscale2 = ((quad & 1) ? cmax[1] : cmax[0]) * (2.0f / 16129.0f);
    // C coefficients pre-scaled by 1/127 (deferred values are 127*h)
    const float c0i = Cvec[s0 + r0] * (1.0f / 127.0f);
    const float c1i = Cvec[s0 + r0 + 1] * (1.0f / 127.0f);

    // prologue: wz for t=0 and t=1; running pointers
    const float2* wzp = wz + (size_t)b * D_ + d;
    float2 wzr[2];
    wzr[0] = wzp[0];
    wzr[1] = wzp[(size_t)B_ * D_];
    wzp += (size_t)2 * B_ * D_;                 // points at t=2's row

    // deferred output state of step t-1: f0/f1 hold 127*tanh values
    float f0 = 0.f, f1 = 0.f, fsil = 0.f;
    float* hp = h_out + (size_t)(1 * B_ + b) * (S_ * D_) + (size_t)s0 * D_ + (size_t)r0 * D_ + d;
    float* op = outputs + (size_t)b * D_ + d;

    __syncthreads();   // full barrier once (init visibility incl. global)

// PF = 1: prefetch wz for t+2 (main body); PF = 0: last two steps, no prefetch.
#define STEP(t, CUR, NXT, PF)                                                  \
    {                                                                          \
        const signed char* ap = &hA8[CUR][l16 & 3][quad * 16];                 \
        int4v Af0 = *(const int4v*)(ap);                                       \
        int4v Af1 = *(const int4v*)(ap + 64);                                  \
        int4v Af2 = *(const int4v*)(ap + 128);                                 \
        int4v Af3 = *(const int4v*)(ap + 192);                                 \
        if ((t) >= 1) { /* step t-1's output path, in the ds_read shadow */    \
            float hv0 = f0 * (1.0f / 127.0f);                                  \
            float hv1 = f1 * (1.0f / 127.0f);                                  \
            __builtin_nontemporal_store(hv0, hp);                              \
            __builtin_nontemporal_store(hv1, hp + D_);                         \
            hp += B_ * S_ * D_;                                                \
            float part = __builtin_fmaf(c0i, f0, c1i * f1);                    \
            part += __shfl_xor(part, 32, 64);  /* combine slot-pairs */        \
            if (quad < 2) atomicAdd(op, part * fsil);                          \
            op += B_ * D_;                                                     \
        }                                                                      \
        float wx2 = wzr[CUR].x + wzr[CUR].x;                                   \
        fsil      = wzr[CUR].y;                                                \
        if (PF) { wzr[CUR] = *wzp; wzp += (size_t)B_ * D_; }                   \
        /* 4 independent 2-deep MFMA chains; dep pairs 4 instrs apart */       \
        int4v a0a = {0, 0, 0, 0}, a0b = a0a, a1a = a0a, a1b = a0a;             \
        a0a = __builtin_amdgcn_mfma_i32_16x16x64_i8(Af0, Bf[0][0], a0a, 0, 0, 0); \
        a1a = __builtin_amdgcn_mfma_i32_16x16x64_i8(Af0, Bf[0][1], a1a, 0, 0, 0); \
        a0b = __builtin_amdgcn_mfma_i32_16x16x64_i8(Af1, Bf[1][0], a0b, 0, 0, 0); \
        a1b = __builtin_amdgcn_mfma_i32_16x16x64_i8(Af1, Bf[1][1], a1b, 0, 0, 0); \
        a0a = __builtin_amdgcn_mfma_i32_16x16x64_i8(Af2, Bf[2][0], a0a, 0, 0, 0); \
        a1a = __builtin_amdgcn_mfma_i32_16x16x64_i8(Af2, Bf[2][1], a1a, 0, 0, 0); \
        a0b = __builtin_amdgcn_mfma_i32_16x16x64_i8(Af3, Bf[3][0], a0b, 0, 0, 0); \
        a1b = __builtin_amdgcn_mfma_i32_16x16x64_i8(Af3, Bf[3][1], a1b, 0, 0, 0); \
        /* select per chain (C rows quad-replicated), then add chain halves */ \
        int u0 = (quad & 2) ? a0a[2] : a0a[0];                                 \
        int u1 = (quad & 2) ? a0b[2] : a0b[0];                                 \
        int v0 = (quad & 2) ? a1a[2] : a1a[0];                                 \
        int v1 = (quad & 2) ? a1b[2] : a1b[0];                                 \
        int sa = (quad & 1) ? (v0 + v1) : (u0 + u1);                           \
        int u2 = (quad & 2) ? a0a[3] : a0a[1];                                 \
        int u3 = (quad & 2) ? a0b[3] : a0b[1];                                 \
        int v2 = (quad & 2) ? a1a[3] : a1a[1];                                 \
        int v3 = (quad & 2) ? a1b[3] : a1b[1];                                 \
        int sb = (quad & 1) ? (v2 + v3) : (u2 + u3);                           \
        /* 127*tanh(pre) = 127 - 254/(exp(2*pre)+1); minimal chain to LDS */   \
        float e0 = __expf(__builtin_fmaf((float)sa, dscale2, wx2));            \
        float e1 = __expf(__builtin_fmaf((float)sb, dscale2, wx2));            \
        float g0 = __builtin_fmaf(-254.0f, __builtin_amdgcn_rcpf(e0 + 1.0f), 127.0f); \
        float g1 = __builtin_fmaf(-254.0f, __builtin_amdgcn_rcpf(e1 + 1.0f), 127.0f); \
        hA8[NXT][r0][d]     = (signed char)__float2int_rn(g0);                 \
        hA8[NXT][r0 + 1][d] = (signed char)__float2int_rn(g1);                 \
        f0 = g0; f1 = g1;                                                      \
        LDS_BARRIER();                                                         \
    }

    for (int t2 = 0; t2 < T_ - 2; t2 += 2) {
        STEP(t2, 0, 1, 1)
        STEP(t2 + 1, 1, 0, 1)
    }
    STEP(T_ - 2, 0, 1, 0)
    STEP(T_ - 1, 1, 0, 0)
#undef STEP

    // tail: flush step T-1's output path
    {
        float hv0 = f0 * (1.0f / 127.0f);
        float hv1 = f1 * (1.0f / 127.0f);
        __builtin_nontemporal_store(hv0, hp);
        __builtin_nontemporal_store(hv1, hp + D_);
        float part = __builtin_fmaf(c0i, f0, c1i * f1);
        part += __shfl_xor(part, 32, 64);
        if (quad < 2) atomicAdd(op, part * fsil);
    }
}

extern "C" void kernel_launch(void* const* d_in, const int* in_sizes, int n_in,
                              void* d_out, int out_size, void* d_ws, size_t ws_size,
                              hipStream_t stream) {
    const float* x    = (const float*)d_in[0];
    const float* z    = (const float*)d_in[1];
    const float* h0   = (const float*)d_in[2];
    const float* W_x  = (const float*)d_in[3];
    const float* W_h  = (const float*)d_in[4];
    const float* bias = (const float*)d_in[5];
    const float* C    = (const float*)d_in[6];

    float* outputs = (float*)d_out;                     // [T*B*D]
    float* h_out   = outputs + (size_t)T_ * B_ * D_;    // [(T+1)*B*S*D]

    float*  WxT = (float*)d_ws;                         // D*D floats
    float2* wz  = (float2*)(WxT + D_ * D_);             // T*B*D float2

    hipMemsetAsync(outputs, 0, (size_t)T_ * B_ * D_ * sizeof(float), stream);
    k_transpose<<<64, 1024, 0, stream>>>(W_x, WxT);
    k_wxall<<<T_ * B_ / 16, 256, 0, stream>>>(x, z, WxT, bias, wz);
    k_rec<<<B_ * S_ / 4, 512, 0, stream>>>(W_h, wz, h0, C, outputs, h_out);
}